// Round 10
// baseline (126.989 us; speedup 1.0000x reference)
//
#include <hip/hip_runtime.h>

// GraphSAGE 2-layer: N=50000, D=128, DEG=16.
// R12: R9 champion base + latency-hiding polish:
//  - direct per-thread neighbor-id loads (no Nl LDS, no first barrier)
//  - bfrag weight loads issued between gather slot0 convert and slot1 issue
//    (L2 latency hides under slot1 work; peak ~120 VGPR keeps 4 blocks/CU)
//  - self/id loads issued at kernel entry
// Model: gather = 800K L2-line requests/layer (1 line/neighbor, minimal) at
// L2 request-throughput floor (~20us/layer); this round shrinks the ~14us/layer
// non-gather remainder.
typedef __attribute__((ext_vector_type(8))) short short8;
typedef __attribute__((ext_vector_type(4))) float f32x4;
typedef __attribute__((ext_vector_type(2))) float f32x2;

#define N_NODES 50000
#define D 128
#define DEG 16
#define BM 32

static __device__ __forceinline__ unsigned short f2b(float f) {
    union { float f; unsigned int u; } v; v.f = f;
    return (unsigned short)((v.u + 0x7fffu + ((v.u >> 16) & 1u)) >> 16);
}

// ---- prep ---- (identical to R9)
__global__ void prep(const float* __restrict__ x, unsigned short* __restrict__ xb,
                     unsigned char* __restrict__ xq,
                     const float* __restrict__ W1, const float* __restrict__ W2,
                     unsigned short* __restrict__ Wf1, unsigned short* __restrict__ Wf2) {
    int b = blockIdx.x;
    if (b < 32) {
        int o  = (b * 256 + threadIdx.x) * 4;
        int e0 = o & 7;
        int l  = (o >> 3) & 63;
        int ct = (o >> 9) & 1;
        int kk = (o >> 10) & 7;
        int w  = o >> 13;
        int n  = w * 32 + ((l & 15) << 1) + ct;
        int kb = kk * 32 + (l >> 4) * 8 + e0;
        ushort4 a, c;
        a.x = f2b(W1[(kb + 0) * D + n]);
        a.y = f2b(W1[(kb + 1) * D + n]);
        a.z = f2b(W1[(kb + 2) * D + n]);
        a.w = f2b(W1[(kb + 3) * D + n]);
        *(ushort4*)(Wf1 + o) = a;
        c.x = f2b(W2[(kb + 0) * D + n]);
        c.y = f2b(W2[(kb + 1) * D + n]);
        c.z = f2b(W2[(kb + 2) * D + n]);
        c.w = f2b(W2[(kb + 3) * D + n]);
        *(ushort4*)(Wf2 + o) = c;
    } else {
        int i = ((b - 32) * 256 + threadIdx.x) * 4;
        if (i < N_NODES * D) {
            float4 v = *(const float4*)(x + i);
            ushort4 o4;
            o4.x = f2b(v.x); o4.y = f2b(v.y); o4.z = f2b(v.z); o4.w = f2b(v.w);
            *(ushort4*)(xb + i) = o4;
            int q = __builtin_amdgcn_cvt_pk_fp8_f32(v.x, v.y, 0, false);
            q = __builtin_amdgcn_cvt_pk_fp8_f32(v.z, v.w, q, true);
            *(unsigned*)(xq + i) = (unsigned)q;
        }
    }
}

// ---- fused layer: out = relu( [feat | mean_nbr(feat_q)] @ W + b ) ----
template <int OUT_BF16>
__global__ __launch_bounds__(256, 4)
void sage_layer(const unsigned short* __restrict__ feat,   // N x D bf16
                const unsigned char* __restrict__ featq,   // N x D fp8
                const int* __restrict__ nbr,               // N x DEG
                const unsigned short* __restrict__ wf,     // fragment-packed bf16
                const float* __restrict__ bias,            // D f32
                void* __restrict__ out,
                unsigned char* __restrict__ outq)          // N x D fp8 (OUT_BF16)
{
    __shared__ __align__(16) unsigned short Hl[BM * 264];  // A tile, row stride 264
    const int tid  = threadIdx.x;
    const int row0 = blockIdx.x * BM;

    const char* fb = (const char*)feat;      // bf16 rows: 256B
    const char* qb = (const char*)featq;     // fp8 rows: 128B

    const int lane = tid & 63;
    const int w    = tid >> 6;
    const int quad = lane >> 4;
    const int l16  = lane & 15;

    // ---- early issue: ids + self rows for both slots (no dependencies)
    const int r0 = tid >> 4;                 // 0..15
    const int r1 = r0 + 16;                  // 16..31
    const int s  = tid & 15;
    const unsigned sB16 = (unsigned)s * 16u;
    const unsigned sB8  = (unsigned)s * 8u;
    int g0 = row0 + r0; if (g0 >= N_NODES) g0 = N_NODES - 1;
    int g1 = row0 + r1; if (g1 >= N_NODES) g1 = N_NODES - 1;

    const int4* np0 = (const int4*)(nbr + (unsigned)g0 * DEG);
    const int4* np1 = (const int4*)(nbr + (unsigned)g1 * DEG);
    int4 ia0 = np0[0], ia1 = np0[1], ia2 = np0[2], ia3 = np0[3];
    int4 ib0 = np1[0], ib1 = np1[1], ib2 = np1[2], ib3 = np1[3];
    short8 self0 = *(const short8*)(fb + (unsigned)g0 * 256u + sB16);
    short8 self1 = *(const short8*)(fb + (unsigned)g1 * 256u + sB16);

    // ---- slot 0: issue 16 gather loads (dependent on ia*)
    int ids0[16] = { ia0.x, ia0.y, ia0.z, ia0.w, ia1.x, ia1.y, ia1.z, ia1.w,
                     ia2.x, ia2.y, ia2.z, ia2.w, ia3.x, ia3.y, ia3.z, ia3.w };
    uint2 v0[16];
    #pragma unroll
    for (int j = 0; j < 16; ++j)
        v0[j] = *(const uint2*)(qb + (((unsigned)ids0[j]) << 7) + sB8);

    // ---- slot 0 convert + LDS write
    f32x2 am0[4];
    #pragma unroll
    for (int i = 0; i < 4; ++i) am0[i] = (f32x2){0.f, 0.f};
    #pragma unroll
    for (int j = 0; j < 16; ++j) {
        am0[0] += __builtin_amdgcn_cvt_pk_f32_fp8(v0[j].x, false);
        am0[1] += __builtin_amdgcn_cvt_pk_f32_fp8(v0[j].x, true);
        am0[2] += __builtin_amdgcn_cvt_pk_f32_fp8(v0[j].y, false);
        am0[3] += __builtin_amdgcn_cvt_pk_f32_fp8(v0[j].y, true);
    }
    {
        unsigned short* hr0 = Hl + r0 * 264 + s * 8;
        *(short8*)(hr0) = self0;
        union { unsigned short u[8]; short8 s8; } m;
        #pragma unroll
        for (int i = 0; i < 4; ++i) {
            m.u[2 * i]     = f2b(am0[i].x * 0.0625f);
            m.u[2 * i + 1] = f2b(am0[i].y * 0.0625f);
        }
        *(short8*)(hr0 + D) = m.s8;
    }

    // ---- bfrag issue (L2 latency hides under slot 1 below)
    const unsigned short* wfw = wf + w * 8192;
    short8 bfrag[8][2];
    #pragma unroll
    for (int kk = 0; kk < 8; ++kk)
        #pragma unroll
        for (int ct = 0; ct < 2; ++ct)
            bfrag[kk][ct] = *(const short8*)(wfw + kk * 1024 + ct * 512 + lane * 8);

    // ---- slot 1: issue + convert + LDS write
    int ids1[16] = { ib0.x, ib0.y, ib0.z, ib0.w, ib1.x, ib1.y, ib1.z, ib1.w,
                     ib2.x, ib2.y, ib2.z, ib2.w, ib3.x, ib3.y, ib3.z, ib3.w };
    uint2 v1[16];
    #pragma unroll
    for (int j = 0; j < 16; ++j)
        v1[j] = *(const uint2*)(qb + (((unsigned)ids1[j]) << 7) + sB8);

    f32x2 am1[4];
    #pragma unroll
    for (int i = 0; i < 4; ++i) am1[i] = (f32x2){0.f, 0.f};
    #pragma unroll
    for (int j = 0; j < 16; ++j) {
        am1[0] += __builtin_amdgcn_cvt_pk_f32_fp8(v1[j].x, false);
        am1[1] += __builtin_amdgcn_cvt_pk_f32_fp8(v1[j].x, true);
        am1[2] += __builtin_amdgcn_cvt_pk_f32_fp8(v1[j].y, false);
        am1[3] += __builtin_amdgcn_cvt_pk_f32_fp8(v1[j].y, true);
    }
    {
        unsigned short* hr1 = Hl + r1 * 264 + s * 8;
        *(short8*)(hr1) = self1;
        union { unsigned short u[8]; short8 s8; } m;
        #pragma unroll
        for (int i = 0; i < 4; ++i) {
            m.u[2 * i]     = f2b(am1[i].x * 0.0625f);
            m.u[2 * i + 1] = f2b(am1[i].y * 0.0625f);
        }
        *(short8*)(hr1 + D) = m.s8;
    }

    __syncthreads();   // only barrier: Hl complete, bfrag already in regs

    // ---- MFMA: 32 rows (2 rt) x 32 cols (2 ct, col-interleaved) per wave
    f32x4 acc[2][2];
    #pragma unroll
    for (int rt = 0; rt < 2; ++rt)
        #pragma unroll
        for (int ct = 0; ct < 2; ++ct)
            acc[rt][ct] = (f32x4){0.f, 0.f, 0.f, 0.f};

    #pragma unroll
    for (int kk = 0; kk < 8; ++kk) {
        short8 af[2];
        #pragma unroll
        for (int rt = 0; rt < 2; ++rt)
            af[rt] = *(const short8*)(&Hl[(rt * 16 + l16) * 264 + kk * 32 + quad * 8]);
        #pragma unroll
        for (int rt = 0; rt < 2; ++rt)
            #pragma unroll
            for (int ct = 0; ct < 2; ++ct)
                acc[rt][ct] = __builtin_amdgcn_mfma_f32_16x16x32_bf16(
                    af[rt], bfrag[kk][ct], acc[rt][ct], 0, 0, 0);
    }

    // ---- epilogue: adjacent col pair (col0, col0+1) per thread
    const int col0 = w * 32 + (l16 << 1);
    float2 bv = *(const float2*)(bias + col0);
    #pragma unroll
    for (int rt = 0; rt < 2; ++rt) {
        int gb = row0 + rt * 16 + quad * 4;
        #pragma unroll
        for (int r = 0; r < 4; ++r) {
            int grow = gb + r;
            if (grow >= N_NODES) continue;
            float v0 = acc[rt][0][r] + bv.x;
            float v1 = acc[rt][1][r] + bv.y;
            v0 = v0 > 0.f ? v0 : 0.f;
            v1 = v1 > 0.f ? v1 : 0.f;
            if (OUT_BF16) {
                unsigned u = (unsigned)f2b(v0) | ((unsigned)f2b(v1) << 16);
                *(unsigned*)((unsigned short*)out + grow * D + col0) = u;
                int q = __builtin_amdgcn_cvt_pk_fp8_f32(v0, v1, 0, false);
                *(unsigned short*)(outq + grow * D + col0) = (unsigned short)q;
            } else {
                f32x2 o2; o2.x = v0; o2.y = v1;
                *(f32x2*)((float*)out + grow * D + col0) = o2;
            }
        }
    }
}

extern "C" void kernel_launch(void* const* d_in, const int* in_sizes, int n_in,
                              void* d_out, int out_size, void* d_ws, size_t ws_size,
                              hipStream_t stream) {
    const float* x  = (const float*)d_in[0];
    const int*   nb = (const int*)d_in[1];
    const float* W1 = (const float*)d_in[2];
    const float* b1 = (const float*)d_in[3];
    const float* W2 = (const float*)d_in[4];
    const float* b2 = (const float*)d_in[5];

    char* ws = (char*)d_ws;
    unsigned short* Wf1 = (unsigned short*)(ws);                       // 64 KB
    unsigned short* Wf2 = (unsigned short*)(ws + 65536);               // 64 KB
    unsigned short* xb  = (unsigned short*)(ws + 131072);              // 12.8 MB
    unsigned short* h1  = (unsigned short*)(ws + 131072 + 12800000);   // 12.8 MB
    unsigned char*  xq  = (unsigned char*)(ws + 131072 + 25600000);    // 6.4 MB
    unsigned char*  h1q = (unsigned char*)(ws + 131072 + 32000000);    // 6.4 MB

    prep<<<32 + 6250, 256, 0, stream>>>(x, xb, xq, W1, W2, Wf1, Wf2);

    const int mgrid = (N_NODES + BM - 1) / BM;  // 1563
    sage_layer<1><<<mgrid, 256, 0, stream>>>(xb, xq, nb, Wf1, b1, h1, h1q);
    sage_layer<0><<<mgrid, 256, 0, stream>>>(h1, h1q, nb, Wf2, b2, d_out, nullptr);
}

// Round 12
// 124.899 us; speedup vs baseline: 1.0167x; 1.0167x over previous
//
#include <hip/hip_runtime.h>

// GraphSAGE 2-layer: N=50000, D=128, DEG=16.
// R14: R9 champion numerics (bf16 h1 self-path, fp8 gather tables) minus the
//      redundant xb copy: layer-1 self reads x (f32) directly, rounding to
//      bf16 in-kernel (bit-identical to R9's xb values). Prep = W-pack + x->fp8
//      only. R13's fp8 self-term failed accuracy (0.066 > 0.053) - reverted.
typedef __attribute__((ext_vector_type(8))) short short8;
typedef __attribute__((ext_vector_type(4))) float f32x4;
typedef __attribute__((ext_vector_type(2))) float f32x2;

#define N_NODES 50000
#define D 128
#define DEG 16
#define BM 32

static __device__ __forceinline__ unsigned short f2b(float f) {
    union { float f; unsigned int u; } v; v.f = f;
    return (unsigned short)((v.u + 0x7fffu + ((v.u >> 16) & 1u)) >> 16);
}

// ---- prep ----
// blocks 0..31: pack W1,W2 ((2D,D) row-major) into fragment order:
//   o = w*8192 + kk*1024 + ct*512 + lane*8 + e  (shorts)
//   k = kk*32 + (lane>>4)*8 + e,  n = w*32 + 2*(lane&15) + ct  (col-interleaved)
// blocks 32..: x -> fp8-e4m3 gather table (xq), 16 floats/thread.
__global__ void prep(const float* __restrict__ x, unsigned char* __restrict__ xq,
                     const float* __restrict__ W1, const float* __restrict__ W2,
                     unsigned short* __restrict__ Wf1, unsigned short* __restrict__ Wf2) {
    int b = blockIdx.x;
    if (b < 32) {
        int o  = (b * 256 + threadIdx.x) * 4;
        int e0 = o & 7;
        int l  = (o >> 3) & 63;
        int ct = (o >> 9) & 1;
        int kk = (o >> 10) & 7;
        int w  = o >> 13;
        int n  = w * 32 + ((l & 15) << 1) + ct;
        int kb = kk * 32 + (l >> 4) * 8 + e0;
        ushort4 a, c;
        a.x = f2b(W1[(kb + 0) * D + n]);
        a.y = f2b(W1[(kb + 1) * D + n]);
        a.z = f2b(W1[(kb + 2) * D + n]);
        a.w = f2b(W1[(kb + 3) * D + n]);
        *(ushort4*)(Wf1 + o) = a;
        c.x = f2b(W2[(kb + 0) * D + n]);
        c.y = f2b(W2[(kb + 1) * D + n]);
        c.z = f2b(W2[(kb + 2) * D + n]);
        c.w = f2b(W2[(kb + 3) * D + n]);
        *(ushort4*)(Wf2 + o) = c;
    } else {
        int i = ((b - 32) * 256 + threadIdx.x) * 16;
        if (i + 16 <= N_NODES * D) {
            float4 v0 = *(const float4*)(x + i);
            float4 v1 = *(const float4*)(x + i + 4);
            float4 v2 = *(const float4*)(x + i + 8);
            float4 v3 = *(const float4*)(x + i + 12);
            int q0 = __builtin_amdgcn_cvt_pk_fp8_f32(v0.x, v0.y, 0, false);
            q0 = __builtin_amdgcn_cvt_pk_fp8_f32(v0.z, v0.w, q0, true);
            int q1 = __builtin_amdgcn_cvt_pk_fp8_f32(v1.x, v1.y, 0, false);
            q1 = __builtin_amdgcn_cvt_pk_fp8_f32(v1.z, v1.w, q1, true);
            int q2 = __builtin_amdgcn_cvt_pk_fp8_f32(v2.x, v2.y, 0, false);
            q2 = __builtin_amdgcn_cvt_pk_fp8_f32(v2.z, v2.w, q2, true);
            int q3 = __builtin_amdgcn_cvt_pk_fp8_f32(v3.x, v3.y, 0, false);
            q3 = __builtin_amdgcn_cvt_pk_fp8_f32(v3.z, v3.w, q3, true);
            uint4 q; q.x = (unsigned)q0; q.y = (unsigned)q1;
            q.z = (unsigned)q2; q.w = (unsigned)q3;
            *(uint4*)(xq + i) = q;
        }
    }
}

// ---- fused layer: out = relu( [self | mean_nbr(featq)] @ W + b ) ----
// LAYER==1: self from x (f32, rounded to bf16 in-kernel); writes h1 bf16 + h1q fp8.
// LAYER==2: self from h1 (bf16); writes f32 final.
template <int LAYER>
__global__ __launch_bounds__(256, 4)
void sage_layer(const void* __restrict__ selfp,            // f32 x | bf16 h1
                const unsigned char* __restrict__ featq,   // N x D fp8 gather table
                const int* __restrict__ nbr,               // N x DEG
                const unsigned short* __restrict__ wf,     // fragment-packed bf16
                const float* __restrict__ bias,            // D f32
                void* __restrict__ out,                    // bf16 h1 | f32 final
                unsigned char* __restrict__ outq)          // fp8 h1q (LAYER==1)
{
    __shared__ __align__(16) unsigned short Hl[BM * 264];  // A tile, row stride 264
    __shared__ int Nl[BM * DEG];                           // 512 neighbor ids
    const int tid  = threadIdx.x;
    const int row0 = blockIdx.x * BM;

    if (tid < 128) {
        int g = row0 * DEG + tid * 4;
        int gmax = N_NODES * DEG - 4;
        if (g > gmax) g = gmax;              // tail clamp; extra rows unused
        *(int4*)(Nl + tid * 4) = *(const int4*)(nbr + g);
    }
    __syncthreads();

    const char* qb = (const char*)featq;     // fp8 rows: 128B

    // ---- gather: 2 (row, 8-dim-slice) pairs per thread; 16 8B-loads in flight
    #pragma unroll
    for (int p = 0; p < 2; ++p) {
        int a = tid + p * 256;
        int r = a >> 4;                      // 0..31
        int s = a & 15;                      // 8-dim slice
        int grow = row0 + r;
        if (grow >= N_NODES) grow = N_NODES - 1;

        // self slice -> bf16x8 (LAYER1: f32 stream, rounds exactly as R9's xb)
        union { unsigned short u[8]; short8 s8; } sf;
        if (LAYER == 1) {
            const float* xf = (const float*)selfp;
            float4 sv0 = *(const float4*)(xf + (unsigned)grow * 128u + s * 8);
            float4 sv1 = *(const float4*)(xf + (unsigned)grow * 128u + s * 8 + 4);
            sf.u[0] = f2b(sv0.x); sf.u[1] = f2b(sv0.y);
            sf.u[2] = f2b(sv0.z); sf.u[3] = f2b(sv0.w);
            sf.u[4] = f2b(sv1.x); sf.u[5] = f2b(sv1.y);
            sf.u[6] = f2b(sv1.z); sf.u[7] = f2b(sv1.w);
        } else {
            sf.s8 = *(const short8*)((const char*)selfp + (unsigned)grow * 256u
                                     + (unsigned)s * 16u);
        }

        int4 i0 = *(const int4*)(Nl + r * 16);
        int4 i1 = *(const int4*)(Nl + r * 16 + 4);
        int4 i2 = *(const int4*)(Nl + r * 16 + 8);
        int4 i3 = *(const int4*)(Nl + r * 16 + 12);
        int ids[16] = { i0.x, i0.y, i0.z, i0.w, i1.x, i1.y, i1.z, i1.w,
                        i2.x, i2.y, i2.z, i2.w, i3.x, i3.y, i3.z, i3.w };

        uint2 v[16];
        #pragma unroll
        for (int j = 0; j < 16; ++j)
            v[j] = *(const uint2*)(qb + (((unsigned)ids[j]) << 7) + (unsigned)s * 8u);

        f32x2 am[4];
        #pragma unroll
        for (int i = 0; i < 4; ++i) am[i] = (f32x2){0.f, 0.f};
        #pragma unroll
        for (int j = 0; j < 16; ++j) {
            am[0] += __builtin_amdgcn_cvt_pk_f32_fp8(v[j].x, false);
            am[1] += __builtin_amdgcn_cvt_pk_f32_fp8(v[j].x, true);
            am[2] += __builtin_amdgcn_cvt_pk_f32_fp8(v[j].y, false);
            am[3] += __builtin_amdgcn_cvt_pk_f32_fp8(v[j].y, true);
        }

        unsigned short* hr = Hl + r * 264 + s * 8;
        *(short8*)(hr) = sf.s8;
        union { unsigned short u[8]; short8 s8; } m;
        #pragma unroll
        for (int i = 0; i < 4; ++i) {
            m.u[2 * i]     = f2b(am[i].x * 0.0625f);
            m.u[2 * i + 1] = f2b(am[i].y * 0.0625f);
        }
        *(short8*)(hr + D) = m.s8;
    }

    // ---- B fragments (fragment-packed: 64 lanes x 16B contiguous per load)
    const int lane = tid & 63;
    const int w    = tid >> 6;
    const int quad = lane >> 4;
    const int l16  = lane & 15;
    const unsigned short* wfw = wf + w * 8192;
    short8 bfrag[8][2];
    #pragma unroll
    for (int kk = 0; kk < 8; ++kk)
        #pragma unroll
        for (int ct = 0; ct < 2; ++ct)
            bfrag[kk][ct] = *(const short8*)(wfw + kk * 1024 + ct * 512 + lane * 8);

    __syncthreads();

    // ---- MFMA: 32 rows (2 rt) x 32 cols (2 ct, col-interleaved) per wave
    f32x4 acc[2][2];
    #pragma unroll
    for (int rt = 0; rt < 2; ++rt)
        #pragma unroll
        for (int ct = 0; ct < 2; ++ct)
            acc[rt][ct] = (f32x4){0.f, 0.f, 0.f, 0.f};

    #pragma unroll
    for (int kk = 0; kk < 8; ++kk) {
        short8 af[2];
        #pragma unroll
        for (int rt = 0; rt < 2; ++rt)
            af[rt] = *(const short8*)(&Hl[(rt * 16 + l16) * 264 + kk * 32 + quad * 8]);
        #pragma unroll
        for (int rt = 0; rt < 2; ++rt)
            #pragma unroll
            for (int ct = 0; ct < 2; ++ct)
                acc[rt][ct] = __builtin_amdgcn_mfma_f32_16x16x32_bf16(
                    af[rt], bfrag[kk][ct], acc[rt][ct], 0, 0, 0);
    }

    // ---- epilogue: adjacent col pair (col0, col0+1) per thread
    const int col0 = w * 32 + (l16 << 1);
    float2 bv = *(const float2*)(bias + col0);
    #pragma unroll
    for (int rt = 0; rt < 2; ++rt) {
        int gb = row0 + rt * 16 + quad * 4;
        #pragma unroll
        for (int r = 0; r < 4; ++r) {
            int grow = gb + r;
            if (grow >= N_NODES) continue;
            float v0 = acc[rt][0][r] + bv.x;
            float v1 = acc[rt][1][r] + bv.y;
            v0 = v0 > 0.f ? v0 : 0.f;
            v1 = v1 > 0.f ? v1 : 0.f;
            if (LAYER == 1) {
                unsigned u = (unsigned)f2b(v0) | ((unsigned)f2b(v1) << 16);
                *(unsigned*)((unsigned short*)out + grow * D + col0) = u;
                int q = __builtin_amdgcn_cvt_pk_fp8_f32(v0, v1, 0, false);
                *(unsigned short*)(outq + grow * D + col0) = (unsigned short)q;
            } else {
                f32x2 o2; o2.x = v0; o2.y = v1;
                *(f32x2*)((float*)out + grow * D + col0) = o2;
            }
        }
    }
}

extern "C" void kernel_launch(void* const* d_in, const int* in_sizes, int n_in,
                              void* d_out, int out_size, void* d_ws, size_t ws_size,
                              hipStream_t stream) {
    const float* x  = (const float*)d_in[0];
    const int*   nb = (const int*)d_in[1];
    const float* W1 = (const float*)d_in[2];
    const float* b1 = (const float*)d_in[3];
    const float* W2 = (const float*)d_in[4];
    const float* b2 = (const float*)d_in[5];

    char* ws = (char*)d_ws;
    unsigned short* Wf1 = (unsigned short*)(ws);                       // 64 KB
    unsigned short* Wf2 = (unsigned short*)(ws + 65536);               // 64 KB
    unsigned char*  xq  = (unsigned char*)(ws + 131072);               // 6.4 MB
    unsigned char*  h1q = (unsigned char*)(ws + 131072 + 6400000);     // 6.4 MB
    unsigned short* h1  = (unsigned short*)(ws + 131072 + 12800000);   // 12.8 MB

    prep<<<32 + 1563, 256, 0, stream>>>(x, xq, W1, W2, Wf1, Wf2);

    const int mgrid = (N_NODES + BM - 1) / BM;  // 1563
    sage_layer<1><<<mgrid, 256, 0, stream>>>((const void*)x, xq, nb, Wf1, b1,
                                             (void*)h1, h1q);
    sage_layer<2><<<mgrid, 256, 0, stream>>>((const void*)h1, h1q, nb, Wf2, b2,
                                             d_out, nullptr);
}